// Round 2
// baseline (411.638 us; speedup 1.0000x reference)
//
#include <hip/hip_runtime.h>
#include <hip/hip_bf16.h>
#include <stdint.h>

typedef __attribute__((ext_vector_type(8))) short bf16x8;
typedef __attribute__((ext_vector_type(4))) float f32x4;

#define NSRC 100000
#define WIN_OFF 0                    // Win[0:256] A-frag pack, 128 KB
#define W1P_OFF (128*1024)           // W1 A-frag pack, 128 KB
#define BU_OFF  (256*1024)           // float2 bu[256] = (b1[f], u[f])
#define SS_OFF  (BU_OFF + 2048)      // float S = b2.w0 + b_out0
#define Y_OFF   (264*1024)           // bf16 Y[NSRC][256] (512 B rows)
#define SORT_OFF (Y_OFF + (size_t)NSRC*512)

#define SHIFT 4
#define NBUCK ((NSRC + (1<<SHIFT) - 1) >> SHIFT)   // 6250 buckets of 16 cols

#define PAIRB 1040                   // 2 rows (1024 B) + 16 B pad -> 2-way max bank alias
#define XBYTES (32*PAIRB)            // 33280 B per buffer (64 rows)
#define POFF(r) (((r)>>1)*PAIRB + ((r)&1)*512)

#define AS3U32(p) ((__attribute__((address_space(3))) uint32_t*)(uintptr_t)(p))
#define AS1U32(p) ((const __attribute__((address_space(1))) uint32_t*)(uintptr_t)(p))

// A-frag-direct pack: frag for (k-chunk c, feature m, quad q) holds W[k=c*32+q*8+j][m]
// at byte offset c*16384 + m*64 + q*16.  Blocks 25.. zero the sort histogram (only
// launched when the workspace has room for the sort buffers).
__global__ __launch_bounds__(256) void pack_kernel(
    const float* __restrict__ Win, const float* __restrict__ W1,
    const float* __restrict__ W2, const float* __restrict__ Wout,
    const float* __restrict__ b1, const float* __restrict__ b2,
    const float* __restrict__ b_out, char* __restrict__ wp,
    int* __restrict__ hist)
{
    const int t = threadIdx.x, blk = blockIdx.x;
    if (blk < 16) {                            // A-frag packs (coalesced row reads)
        const float* W = (blk < 8) ? Win : W1;
        char* dst = wp + ((blk < 8) ? WIN_OFF : W1P_OFF);
        const int c = blk & 7;
        #pragma unroll
        for (int q = 0; q < 4; ++q) {
            union { bf16x8 v; __hip_bfloat16 h[8]; } u;
            #pragma unroll
            for (int j = 0; j < 8; ++j)
                u.h[j] = __float2bfloat16(W[(size_t)(c*32 + q*8 + j)*256 + t]);
            *(bf16x8*)(dst + c*16384 + t*64 + q*16) = u.v;
        }
    } else if (blk < 24) {                     // u[f] = sum_n W2[f][n]*w0[n]; bu=(b1,u)
        __shared__ float w0s[256];
        w0s[t] = Wout[t*2];
        __syncthreads();
        const int b = blk - 16, fl = t >> 3, sub = t & 7, f = b*32 + fl;
        const float* row = W2 + (size_t)f*256 + sub*32;
        float p = 0.f;
        #pragma unroll
        for (int j = 0; j < 32; ++j) p += row[j]*w0s[sub*32 + j];
        p += __shfl_xor(p,1); p += __shfl_xor(p,2); p += __shfl_xor(p,4);
        if (sub == 0) {
            float2 v; v.x = b1[f]; v.y = p;
            *(float2*)(wp + BU_OFF + f*8) = v;
        }
    } else if (blk == 24) {                    // S = dot(b2,w0) + b_out0
        __shared__ float rb[4];
        float v = b2[t]*Wout[t*2];
        v += __shfl_xor(v,1); v += __shfl_xor(v,2); v += __shfl_xor(v,4);
        v += __shfl_xor(v,8); v += __shfl_xor(v,16); v += __shfl_xor(v,32);
        if ((t&63) == 0) rb[t>>6] = v;
        __syncthreads();
        if (t == 0) *(float*)(wp + SS_OFF) = rb[0]+rb[1]+rb[2]+rb[3] + b_out[0];
    } else {                                   // zero histogram (sort path only)
        const int idx = (blk - 25)*256 + t;
        if (idx < NBUCK) hist[idx] = 0;
    }
}

__global__ __launch_bounds__(256) void hist_kernel(
    const int* __restrict__ coli, int* __restrict__ hist, int E)
{
    int i = blockIdx.x*256 + threadIdx.x;
    for (; i < E; i += gridDim.x*256)
        atomicAdd(&hist[coli[i] >> SHIFT], 1);
}

// single-block exclusive scan of hist[NBUCK] -> off[NBUCK]
__global__ __launch_bounds__(1024) void scan_kernel(
    const int* __restrict__ hist, int* __restrict__ off)
{
    __shared__ int part[1024];
    const int t = threadIdx.x;
    const int base = t * 7;                    // 1024*7 >= NBUCK
    int v[7]; int s = 0;
    #pragma unroll
    for (int j = 0; j < 7; ++j) {
        const int idx = base + j;
        int h = (idx < NBUCK) ? hist[idx] : 0;
        v[j] = s; s += h;                      // exclusive within chunk
    }
    part[t] = s;
    __syncthreads();
    for (int d = 1; d < 1024; d <<= 1) {       // Hillis-Steele inclusive
        int x = (t >= d) ? part[t - d] : 0;
        __syncthreads();
        part[t] += x;
        __syncthreads();
    }
    const int pre = (t == 0) ? 0 : part[t - 1];
    #pragma unroll
    for (int j = 0; j < 7; ++j) {
        const int idx = base + j;
        if (idx < NBUCK) off[idx] = pre + v[j];
    }
}

// bucket-scatter: perm[p] = original edge id, sorted by col>>SHIFT
__global__ __launch_bounds__(256) void scatter_kernel(
    const int* __restrict__ coli, int* __restrict__ off,
    int* __restrict__ perm, int E)
{
    int i = blockIdx.x*256 + threadIdx.x;
    for (; i < E; i += gridDim.x*256) {
        const int c = coli[i];
        const int p = atomicAdd(&off[c >> SHIFT], 1);
        perm[p] = i;
    }
}

// Y[s] = latents[s] @ Win[0:256] + b_in   (bf16, no relu — pos added per-edge later)
__global__ __launch_bounds__(256, 2) void precompute_y(
    const float* __restrict__ latents, const float* __restrict__ b_in,
    const char* __restrict__ wp, char* __restrict__ Yc)
{
    __shared__ __align__(16) char Xs[XBYTES];
    __shared__ float binS[256];
    const int tid = threadIdx.x, wave = tid >> 6, lane = tid & 63;
    const int q = lane >> 4, lm = lane & 15;

    bf16x8 wA[4][8];                           // Win slice: 64 feats/wave, 128 VGPR
    {
        const char* wb = wp + WIN_OFF;
        #pragma unroll
        for (int mt = 0; mt < 4; ++mt) {
            const int m = wave*64 + mt*16 + lm;
            #pragma unroll
            for (int c = 0; c < 8; ++c)
                wA[mt][c] = *(const bf16x8*)(wb + c*16384 + m*64 + q*16);
        }
    }
    binS[tid] = b_in[tid];

    const int ntY = (NSRC + 63) / 64;
    for (int tile = blockIdx.x; tile < ntY; tile += 512) {
        const int base = tile*64;
        {                                      // fp32 latents -> bf16 LDS, coalesced
            const int r = tid & 63, h = tid >> 6;
            int srow = base + r; if (srow >= NSRC) srow = NSRC - 1;
            const float4* lp = (const float4*)(latents + (size_t)srow*256 + h*64);
            #pragma unroll
            for (int w = 0; w < 8; ++w) {
                float4 v0 = lp[w*2], v1 = lp[w*2+1];
                union { bf16x8 v; __hip_bfloat16 hh[8]; } u;
                u.hh[0]=__float2bfloat16(v0.x); u.hh[1]=__float2bfloat16(v0.y);
                u.hh[2]=__float2bfloat16(v0.z); u.hh[3]=__float2bfloat16(v0.w);
                u.hh[4]=__float2bfloat16(v1.x); u.hh[5]=__float2bfloat16(v1.y);
                u.hh[6]=__float2bfloat16(v1.z); u.hh[7]=__float2bfloat16(v1.w);
                *(bf16x8*)(Xs + POFF(r) + h*128 + w*16) = u.v;
            }
        }
        __syncthreads();
        f32x4 acc[4][4];
        #pragma unroll
        for (int mt = 0; mt < 4; ++mt)
            #pragma unroll
            for (int nt = 0; nt < 4; ++nt) acc[mt][nt] = (f32x4){0.f,0.f,0.f,0.f};
        #pragma unroll
        for (int c = 0; c < 8; ++c) {
            bf16x8 b[4];
            #pragma unroll
            for (int nt = 0; nt < 4; ++nt)
                b[nt] = *(const bf16x8*)(Xs + POFF(nt*16+lm) + c*64 + q*16);
            #pragma unroll
            for (int mt = 0; mt < 4; ++mt)
                #pragma unroll
                for (int nt = 0; nt < 4; ++nt)
                    acc[mt][nt] = __builtin_amdgcn_mfma_f32_16x16x32_bf16(wA[mt][c], b[nt], acc[mt][nt], 0,0,0);
        }
        #pragma unroll
        for (int mt = 0; mt < 4; ++mt) {
            const int f0 = wave*64 + mt*16 + q*4;
            float4 bb = *(const float4*)&binS[f0];
            float bbv[4] = {bb.x, bb.y, bb.z, bb.w};
            #pragma unroll
            for (int nt = 0; nt < 4; ++nt) {
                const int srow = base + nt*16 + lm;
                if (srow < NSRC) {
                    union { uint2 uu; __hip_bfloat16 hh[4]; } pk;
                    #pragma unroll
                    for (int rg = 0; rg < 4; ++rg)
                        pk.hh[rg] = __float2bfloat16(acc[mt][nt][rg] + bbv[rg]);
                    *(uint2*)(Yc + (size_t)srow*512 + f0*2) = pk.uu;
                }
            }
        }
        __syncthreads();
    }
}

// out[perm[e]] = relu( relu(Y[col]+pos@Wpos) @ W1 + b1 ) . u + S
// perm != nullptr: edges pre-sorted by col bucket -> gather hits L1/L2
// perm == nullptr: identity order (workspace fallback)
__global__ __launch_bounds__(256, 2) void interp_main(
    const float* __restrict__ pos_src, const float* __restrict__ pos_tgt,
    const int* __restrict__ rowi, const int* __restrict__ coli,
    const int* __restrict__ perm,
    const float* __restrict__ Win, const char* __restrict__ wp,
    const char* __restrict__ Yc, float* __restrict__ out,
    int E, int ntiles)
{
    __shared__ __align__(16) char Xs[2][XBYTES];   // 66560
    __shared__ float wposI[32][24];                // interleaved: [fseg][dim*8+j]
    __shared__ float buS[512];                     // float2[256] = (b1,u)
    __shared__ float posrel[2][64][4];
    __shared__ int   colsS[2][64];
    __shared__ float red[4][64];

    const int tid = threadIdx.x, wave = tid >> 6, lane = tid & 63;
    const int q = lane >> 4, lm = lane & 15;
    const int bid = blockIdx.x;

    bf16x8 wA[4][8];                               // W1 slice, 128 VGPR, loaded once
    {
        const char* wb = wp + W1P_OFF;
        #pragma unroll
        for (int mt = 0; mt < 4; ++mt) {
            const int m = wave*64 + mt*16 + lm;
            #pragma unroll
            for (int c = 0; c < 8; ++c)
                wA[mt][c] = *(const bf16x8*)(wb + c*16384 + m*64 + q*16);
        }
    }
    {
        #pragma unroll
        for (int s = 0; s < 3; ++s)
            wposI[tid >> 3][s*8 + (tid & 7)] = Win[(size_t)(256+s)*256 + tid];
        *(float2*)&buS[tid*2] = *(const float2*)(wp + BU_OFF + tid*8);
    }
    const float Sv = *(const float*)(wp + SS_OFF);
    const int niter = (ntiles - bid + 511) / 512;
    int pe = 0;                                    // output index carry for out-store

    // prologue: meta for iterations 0,1
    #pragma unroll
    for (int ii = 0; ii < 2; ++ii) {
        if (tid < 64) {
            long tt = (long)bid + (long)ii*512; if (tt >= ntiles) tt = ntiles - 1;
            long e = tt*64 + tid; if (e >= E) e = E - 1;
            const int pidx = perm ? perm[e] : (int)e;
            int ri = rowi[pidx], ci = coli[pidx];
            colsS[ii][tid] = ci;
            float4 pr;
            pr.x = pos_tgt[ri*3+0] - pos_src[ci*3+0];
            pr.y = pos_tgt[ri*3+1] - pos_src[ci*3+1];
            pr.z = pos_tgt[ri*3+2] - pos_src[ci*3+2];
            pr.w = 0.f;
            *(float4*)&posrel[ii][tid][0] = pr;
        }
    }
    __syncthreads();
    {                                              // gather tile 0 -> Xs[0]
        #pragma unroll
        for (int k2 = 0; k2 < 8; ++k2) {
            const int r0 = wave*16 + k2*2;
            const int row = r0 + (lane >> 5);
            const int cv = colsS[0][row];
            const char* src = Yc + (size_t)cv*512 + (lane & 31)*16;
            __builtin_amdgcn_global_load_lds(AS1U32(src), AS3U32(Xs[0] + (r0>>1)*PAIRB), 16, 0, 0);
        }
    }

    for (int i = 0; i < niter; ++i) {
        const int p = i & 1;
        __syncthreads();                           // A: gather(i) drained, Xs[p] ready

        // ---- phase1 ----
        if (tid < 64) {
            if (i > 0) {                           // out-store for tile i-1 (scattered)
                long e = ((long)bid + (long)(i-1)*512)*64 + tid;
                if (e < E) out[pe] = red[0][tid]+red[1][tid]+red[2][tid]+red[3][tid] + Sv;
            }
            long ec = ((long)bid + (long)i*512)*64 + tid;   // output index for tile i
            if (ec < E) pe = perm ? perm[ec] : (int)ec;
        }
        int m_ci = 0; float4 m_pr = {0.f,0.f,0.f,0.f};   // meta loads for i+2
        if (tid < 64) {
            long tt = (long)bid + (long)(i+2)*512; if (tt >= ntiles) tt = ntiles - 1;
            long e = tt*64 + tid; if (e >= E) e = E - 1;
            const int pidx = perm ? perm[e] : (int)e;
            int ri = rowi[pidx]; m_ci = coli[pidx];
            m_pr.x = pos_tgt[ri*3+0] - pos_src[m_ci*3+0];
            m_pr.y = pos_tgt[ri*3+1] - pos_src[m_ci*3+1];
            m_pr.z = pos_tgt[ri*3+2] - pos_src[m_ci*3+2];
        }
        {                                          // pos-pass: Xs[p] = relu(Y + pos@Wpos)
            const int fs = tid & 31, rb = tid >> 5;
            float w0v[8], w1v[8], w2v[8];
            {
                const float* wi = &wposI[fs][0];
                #pragma unroll
                for (int j = 0; j < 8; ++j) { w0v[j]=wi[j]; w1v[j]=wi[8+j]; w2v[j]=wi[16+j]; }
            }
            char* xb = Xs[p];
            #pragma unroll
            for (int ii2 = 0; ii2 < 8; ++ii2) {
                const int r = rb*8 + ii2;
                float4 pr = *(const float4*)&posrel[p][r][0];
                char* addr = xb + POFF(r) + fs*16;
                union { bf16x8 v; __hip_bfloat16 h[8]; } u;
                u.v = *(bf16x8*)addr;
                #pragma unroll
                for (int j = 0; j < 8; ++j) {
                    float vv = __bfloat162float(u.h[j]) + pr.x*w0v[j] + pr.y*w1v[j] + pr.z*w2v[j];
                    u.h[j] = __float2bfloat16(vv < 0.f ? 0.f : vv);
                }
                *(bf16x8*)addr = u.v;
            }
        }
        __syncthreads();                           // B

        // ---- phase2 ----
        {                                          // gather(i+1) -> Xs[1-p]; in flight across MFMA
            const int s = 1 - p;
            char* xb = Xs[s];
            #pragma unroll
            for (int k2 = 0; k2 < 8; ++k2) {
                const int r0 = wave*16 + k2*2;
                const int row = r0 + (lane >> 5);
                const int cv = colsS[s][row];
                const char* src = Yc + (size_t)cv*512 + (lane & 31)*16;
                __builtin_amdgcn_global_load_lds(AS1U32(src), AS3U32(xb + (r0>>1)*PAIRB), 16, 0, 0);
            }
        }
        f32x4 acc[4][4];
        #pragma unroll
        for (int mt = 0; mt < 4; ++mt)
            #pragma unroll
            for (int nt = 0; nt < 4; ++nt) acc[mt][nt] = (f32x4){0.f,0.f,0.f,0.f};
        {
            const char* xb = Xs[p];
            #pragma unroll
            for (int c = 0; c < 8; ++c) {
                bf16x8 b[4];
                #pragma unroll
                for (int nt = 0; nt < 4; ++nt)
                    b[nt] = *(const bf16x8*)(xb + POFF(nt*16+lm) + c*64 + q*16);
                #pragma unroll
                for (int mt = 0; mt < 4; ++mt)
                    #pragma unroll
                    for (int nt = 0; nt < 4; ++nt)
                        acc[mt][nt] = __builtin_amdgcn_mfma_f32_16x16x32_bf16(wA[mt][c], b[nt], acc[mt][nt], 0,0,0);
            }
        }
        float partial[4] = {0.f,0.f,0.f,0.f};      // epilogue: relu(h1+b1).u, all fp32
        #pragma unroll
        for (int mt = 0; mt < 4; ++mt) {
            const int f0 = wave*64 + mt*16 + q*4;
            float4 bu0 = *(const float4*)&buS[f0*2];
            float4 bu1 = *(const float4*)&buS[f0*2 + 4];
            float b1v[4] = {bu0.x, bu0.z, bu1.x, bu1.z};
            float uv[4]  = {bu0.y, bu0.w, bu1.y, bu1.w};
            #pragma unroll
            for (int nt = 0; nt < 4; ++nt)
                #pragma unroll
                for (int rg = 0; rg < 4; ++rg) {
                    float h = acc[mt][nt][rg] + b1v[rg];
                    if (h > 0.f) partial[nt] += h * uv[rg];
                }
        }
        #pragma unroll
        for (int nt = 0; nt < 4; ++nt) {
            float v = partial[nt];
            v += __shfl_xor(v, 16);
            v += __shfl_xor(v, 32);
            if (lane < 16) red[wave][nt*16 + lane] = v;
        }
        if (tid < 64) {                            // meta writes for i+2 (slot p)
            colsS[p][tid] = m_ci;
            *(float4*)&posrel[p][tid][0] = m_pr;
        }
    }
    __syncthreads();
    if (tid < 64) {                                // final tile's out-store
        long e = ((long)bid + (long)(niter-1)*512)*64 + tid;
        if (e < E) out[pe] = red[0][tid]+red[1][tid]+red[2][tid]+red[3][tid] + Sv;
    }
}

extern "C" void kernel_launch(void* const* d_in, const int* in_sizes, int n_in,
                              void* d_out, int out_size, void* d_ws, size_t ws_size,
                              hipStream_t stream)
{
    const float* pos_src = (const float*)d_in[0];
    const float* pos_tgt = (const float*)d_in[1];
    const float* latents = (const float*)d_in[2];
    const int*   rowi    = (const int*)d_in[3];
    const int*   coli    = (const int*)d_in[4];
    const float* Win     = (const float*)d_in[5];
    const float* b_in    = (const float*)d_in[6];
    const float* W1      = (const float*)d_in[7];
    const float* b1      = (const float*)d_in[8];
    const float* W2      = (const float*)d_in[9];
    const float* b2      = (const float*)d_in[10];
    const float* Wout    = (const float*)d_in[11];
    const float* b_out   = (const float*)d_in[12];
    float* out = (float*)d_out;
    const int E = in_sizes[3];
    const int ntiles = (E + 63) / 64;

    char* wp = (char*)d_ws;                  // packs 264 KB + Y 51.2 MB [+ sort ~2.1 MB]
    char* Yc = wp + Y_OFF;

    // sort buffers live past Y; only used if the workspace has room
    const size_t sort_need = SORT_OFF + 2*32*1024 + (size_t)E*4;
    const bool use_sort = (ws_size >= sort_need);
    int* hist = (int*)(wp + SORT_OFF);       // 6250 ints (32 KB slot)
    int* off  = hist + 8192;                 // 6250 ints (32 KB slot)
    int* perm = off + 8192;                  // E ints

    pack_kernel<<<use_sort ? 50 : 25, 256, 0, stream>>>(
        Win, W1, W2, Wout, b1, b2, b_out, wp, hist);
    if (use_sort) {
        hist_kernel<<<512, 256, 0, stream>>>(coli, hist, E);
        scan_kernel<<<1, 1024, 0, stream>>>(hist, off);
        scatter_kernel<<<512, 256, 0, stream>>>(coli, off, perm, E);
    }
    precompute_y<<<512, 256, 0, stream>>>(latents, b_in, wp, Yc);
    interp_main<<<512, 256, 0, stream>>>(pos_src, pos_tgt, rowi, coli,
                                         use_sort ? perm : (const int*)nullptr,
                                         Win, wp, Yc, out, E, ntiles);
}

// Round 4
// 304.543 us; speedup vs baseline: 1.3517x; 1.3517x over previous
//
#include <hip/hip_runtime.h>
#include <hip/hip_bf16.h>
#include <stdint.h>

typedef __attribute__((ext_vector_type(8))) short bf16x8;
typedef __attribute__((ext_vector_type(4))) float f32x4;

#define NSRC 100000
#define WIN_OFF 0                    // Win[0:256] A-frag pack, 128 KB
#define W1P_OFF (128*1024)           // W1 A-frag pack, 128 KB
#define BU_OFF  (256*1024)           // float2 bu[256] = (b1[f], u[f])
#define SS_OFF  (BU_OFF + 2048)      // float S = b2.w0 + b_out0
#define Y_OFF   (264*1024)           // bf16 Y[NSRC][256] (512 B rows)

#define PAIRB 1040                   // 2 bf16 rows (1024 B) + 16 B pad
#define XBYTES (32*PAIRB)            // 33280 B per buffer (64 rows)
#define POFF(r) (((r)>>1)*PAIRB + ((r)&1)*512)

#define L32 1040                     // fp32 latents row stride in LDS (1024 + 16)

#define AS3U32(p) ((__attribute__((address_space(3))) uint32_t*)(uintptr_t)(p))
#define AS1U32(p) ((const __attribute__((address_space(1))) uint32_t*)(uintptr_t)(p))

// A-frag-direct pack: frag for (k-chunk c, feature m, quad q) holds W[k=c*32+q*8+j][m]
// at byte offset c*16384 + m*64 + q*16.
__global__ __launch_bounds__(256) void pack_kernel(
    const float* __restrict__ Win, const float* __restrict__ W1,
    const float* __restrict__ W2, const float* __restrict__ Wout,
    const float* __restrict__ b1, const float* __restrict__ b2,
    const float* __restrict__ b_out, char* __restrict__ wp)
{
    const int t = threadIdx.x, blk = blockIdx.x;
    if (blk < 16) {                            // A-frag packs (coalesced row reads)
        const float* W = (blk < 8) ? Win : W1;
        char* dst = wp + ((blk < 8) ? WIN_OFF : W1P_OFF);
        const int c = blk & 7;
        #pragma unroll
        for (int q = 0; q < 4; ++q) {
            union { bf16x8 v; __hip_bfloat16 h[8]; } u;
            #pragma unroll
            for (int j = 0; j < 8; ++j)
                u.h[j] = __float2bfloat16(W[(size_t)(c*32 + q*8 + j)*256 + t]);
            *(bf16x8*)(dst + c*16384 + t*64 + q*16) = u.v;
        }
    } else if (blk < 24) {                     // u[f] = sum_n W2[f][n]*w0[n]; bu=(b1,u)
        __shared__ float w0s[256];
        w0s[t] = Wout[t*2];
        __syncthreads();
        const int b = blk - 16, fl = t >> 3, sub = t & 7, f = b*32 + fl;
        const float* row = W2 + (size_t)f*256 + sub*32;
        float p = 0.f;
        #pragma unroll
        for (int j = 0; j < 32; ++j) p += row[j]*w0s[sub*32 + j];
        p += __shfl_xor(p,1); p += __shfl_xor(p,2); p += __shfl_xor(p,4);
        if (sub == 0) {
            float2 v; v.x = b1[f]; v.y = p;
            *(float2*)(wp + BU_OFF + f*8) = v;
        }
    } else {                                   // S = dot(b2,w0) + b_out0
        __shared__ float rb[4];
        float v = b2[t]*Wout[t*2];
        v += __shfl_xor(v,1); v += __shfl_xor(v,2); v += __shfl_xor(v,4);
        v += __shfl_xor(v,8); v += __shfl_xor(v,16); v += __shfl_xor(v,32);
        if ((t&63) == 0) rb[t>>6] = v;
        __syncthreads();
        if (t == 0) *(float*)(wp + SS_OFF) = rb[0]+rb[1]+rb[2]+rb[3] + b_out[0];
    }
}

// Y[s] = latents[s] @ Win[0:256] + b_in   (bf16, no relu — pos added per-edge later)
// Double-buffered global_load_lds pipeline: stage raw fp32 latents (32-row
// sub-tiles), convert fp32->bf16 in registers during B-fragment load.
__global__ __launch_bounds__(256, 2) void precompute_y(
    const float* __restrict__ latents, const float* __restrict__ b_in,
    const char* __restrict__ wp, char* __restrict__ Yc)
{
    __shared__ __align__(16) char Ls[2][32*L32];   // 2 x 33280 B, fp32 rows
    __shared__ float binS[256];
    const int tid = threadIdx.x, wave = tid >> 6, lane = tid & 63;
    const int q = lane >> 4, lm = lane & 15;

    bf16x8 wA[4][8];                           // Win slice: 64 feats/wave, 128 VGPR
    {
        const char* wb = wp + WIN_OFF;
        #pragma unroll
        for (int mt = 0; mt < 4; ++mt) {
            const int m = wave*64 + mt*16 + lm;
            #pragma unroll
            for (int c = 0; c < 8; ++c)
                wA[mt][c] = *(const bf16x8*)(wb + c*16384 + m*64 + q*16);
        }
    }
    binS[tid] = b_in[tid];

    const int nt32 = NSRC / 32;                // 3125 sub-tiles of 32 src rows
    const int t0 = blockIdx.x;

    // stage sub-tile t (32 fp32 rows of 1024 B) into buf; dest linear per row
    #define STAGE32(t, buf) do {                                               \
        const float* __lat = latents + (size_t)(t)*32*256;                     \
        _Pragma("unroll")                                                      \
        for (int j = 0; j < 8; ++j) {                                          \
            const int r = wave*8 + j;                                          \
            __builtin_amdgcn_global_load_lds(                                  \
                AS1U32((const char*)(__lat + (size_t)r*256) + lane*16),        \
                AS3U32((buf) + r*L32), 16, 0, 0);                              \
        }                                                                      \
    } while (0)

    if (t0 < nt32) STAGE32(t0, Ls[0]);

    int it = 0;
    for (int t = t0; t < nt32; t += 512, ++it) {
        const int p = it & 1;
        __syncthreads();                       // stage(t) drained into Ls[p]
        if (t + 512 < nt32) STAGE32(t + 512, Ls[1 - p]);   // overlap with compute

        f32x4 acc[4][2];
        #pragma unroll
        for (int mt = 0; mt < 4; ++mt)
            #pragma unroll
            for (int nt = 0; nt < 2; ++nt) acc[mt][nt] = (f32x4){0.f,0.f,0.f,0.f};

        const char* lb = Ls[p];
        #pragma unroll
        for (int c = 0; c < 8; ++c) {
            bf16x8 b[2];
            #pragma unroll
            for (int nt = 0; nt < 2; ++nt) {
                const int n = nt*16 + lm;
                const float* fp = (const float*)(lb + n*L32 + c*128 + q*32);
                float4 f0 = *(const float4*)fp;
                float4 f1 = *(const float4*)(fp + 4);
                union { bf16x8 v; __hip_bfloat16 h[8]; } u;
                u.h[0]=__float2bfloat16(f0.x); u.h[1]=__float2bfloat16(f0.y);
                u.h[2]=__float2bfloat16(f0.z); u.h[3]=__float2bfloat16(f0.w);
                u.h[4]=__float2bfloat16(f1.x); u.h[5]=__float2bfloat16(f1.y);
                u.h[6]=__float2bfloat16(f1.z); u.h[7]=__float2bfloat16(f1.w);
                b[nt] = u.v;
            }
            #pragma unroll
            for (int mt = 0; mt < 4; ++mt)
                #pragma unroll
                for (int nt = 0; nt < 2; ++nt)
                    acc[mt][nt] = __builtin_amdgcn_mfma_f32_16x16x32_bf16(wA[mt][c], b[nt], acc[mt][nt], 0,0,0);
        }
        #pragma unroll
        for (int mt = 0; mt < 4; ++mt) {
            const int f0 = wave*64 + mt*16 + q*4;
            float4 bb = *(const float4*)&binS[f0];
            float bbv[4] = {bb.x, bb.y, bb.z, bb.w};
            #pragma unroll
            for (int nt = 0; nt < 2; ++nt) {
                const int srow = t*32 + nt*16 + lm;
                union { uint2 uu; __hip_bfloat16 hh[4]; } pk;
                #pragma unroll
                for (int rg = 0; rg < 4; ++rg)
                    pk.hh[rg] = __float2bfloat16(acc[mt][nt][rg] + bbv[rg]);
                *(uint2*)(Yc + (size_t)srow*512 + f0*2) = pk.uu;
            }
        }
    }
    #undef STAGE32
}

// out[e] = relu( relu(Y[col]+pos@Wpos) @ W1 + b1 ) . u + S
__global__ __launch_bounds__(256, 2) void interp_main(
    const float* __restrict__ pos_src, const float* __restrict__ pos_tgt,
    const int* __restrict__ rowi, const int* __restrict__ coli,
    const float* __restrict__ Win, const char* __restrict__ wp,
    const char* __restrict__ Yc, float* __restrict__ out,
    int E, int ntiles)
{
    __shared__ __align__(16) char Xs[2][XBYTES];   // 66560
    __shared__ float wposI[32][24];                // interleaved: [fseg][dim*8+j]
    __shared__ float buS[512];                     // float2[256] = (b1,u)
    __shared__ float posrel[2][64][4];
    __shared__ int   colsS[2][64];
    __shared__ float red[4][64];

    const int tid = threadIdx.x, wave = tid >> 6, lane = tid & 63;
    const int q = lane >> 4, lm = lane & 15;
    const int bid = blockIdx.x;

    bf16x8 wA[4][8];                               // W1 slice, 128 VGPR, loaded once
    {
        const char* wb = wp + W1P_OFF;
        #pragma unroll
        for (int mt = 0; mt < 4; ++mt) {
            const int m = wave*64 + mt*16 + lm;
            #pragma unroll
            for (int c = 0; c < 8; ++c)
                wA[mt][c] = *(const bf16x8*)(wb + c*16384 + m*64 + q*16);
        }
    }
    {
        #pragma unroll
        for (int s = 0; s < 3; ++s)
            wposI[tid >> 3][s*8 + (tid & 7)] = Win[(size_t)(256+s)*256 + tid];
        *(float2*)&buS[tid*2] = *(const float2*)(wp + BU_OFF + tid*8);
    }
    const float Sv = *(const float*)(wp + SS_OFF);
    const int niter = (ntiles - bid + 511) / 512;

    // prologue: meta for iterations 0,1
    #pragma unroll
    for (int ii = 0; ii < 2; ++ii) {
        if (tid < 64) {
            long tt = (long)bid + (long)ii*512; if (tt >= ntiles) tt = ntiles - 1;
            long e = tt*64 + tid; if (e >= E) e = E - 1;
            int ri = rowi[e], ci = coli[e];
            colsS[ii][tid] = ci;
            float4 pr;
            pr.x = pos_tgt[ri*3+0] - pos_src[ci*3+0];
            pr.y = pos_tgt[ri*3+1] - pos_src[ci*3+1];
            pr.z = pos_tgt[ri*3+2] - pos_src[ci*3+2];
            pr.w = 0.f;
            *(float4*)&posrel[ii][tid][0] = pr;
        }
    }
    __syncthreads();
    {                                              // gather tile 0 -> Xs[0]
        #pragma unroll
        for (int k2 = 0; k2 < 8; ++k2) {
            const int r0 = wave*16 + k2*2;
            const int row = r0 + (lane >> 5);
            const int cv = colsS[0][row];
            const char* src = Yc + (size_t)cv*512 + (lane & 31)*16;
            __builtin_amdgcn_global_load_lds(AS1U32(src), AS3U32(Xs[0] + (r0>>1)*PAIRB), 16, 0, 0);
        }
    }

    for (int i = 0; i < niter; ++i) {
        const int p = i & 1;
        __syncthreads();                           // A: gather(i) drained, Xs[p] ready

        // ---- phase1 ----
        if (i > 0 && tid < 64) {                   // out-store for tile i-1
            long e = ((long)bid + (long)(i-1)*512)*64 + tid;
            if (e < E) out[e] = red[0][tid]+red[1][tid]+red[2][tid]+red[3][tid] + Sv;
        }
        int m_ci = 0; float4 m_pr = {0.f,0.f,0.f,0.f};   // meta loads for i+2
        if (tid < 64) {
            long tt = (long)bid + (long)(i+2)*512; if (tt >= ntiles) tt = ntiles - 1;
            long e = tt*64 + tid; if (e >= E) e = E - 1;
            int ri = rowi[e]; m_ci = coli[e];
            m_pr.x = pos_tgt[ri*3+0] - pos_src[m_ci*3+0];
            m_pr.y = pos_tgt[ri*3+1] - pos_src[m_ci*3+1];
            m_pr.z = pos_tgt[ri*3+2] - pos_src[m_ci*3+2];
        }
        {                                          // pos-pass: Xs[p] = relu(Y + pos@Wpos)
            const int fs = tid & 31, rb = tid >> 5;
            float w0v[8], w1v[8], w2v[8];
            {
                const float* wi = &wposI[fs][0];
                #pragma unroll
                for (int j = 0; j < 8; ++j) { w0v[j]=wi[j]; w1v[j]=wi[8+j]; w2v[j]=wi[16+j]; }
            }
            char* xb = Xs[p];
            #pragma unroll
            for (int ii2 = 0; ii2 < 8; ++ii2) {
                const int r = rb*8 + ii2;
                float4 pr = *(const float4*)&posrel[p][r][0];
                char* addr = xb + POFF(r) + fs*16;
                union { bf16x8 v; __hip_bfloat16 h[8]; } u;
                u.v = *(bf16x8*)addr;
                #pragma unroll
                for (int j = 0; j < 8; ++j) {
                    float vv = __bfloat162float(u.h[j]) + pr.x*w0v[j] + pr.y*w1v[j] + pr.z*w2v[j];
                    u.h[j] = __float2bfloat16(vv < 0.f ? 0.f : vv);
                }
                *(bf16x8*)addr = u.v;
            }
        }
        __syncthreads();                           // B

        // ---- phase2 ----
        {                                          // gather(i+1) -> Xs[1-p]; in flight across MFMA
            const int s = 1 - p;
            char* xb = Xs[s];
            #pragma unroll
            for (int k2 = 0; k2 < 8; ++k2) {
                const int r0 = wave*16 + k2*2;
                const int row = r0 + (lane >> 5);
                const int cv = colsS[s][row];
                const char* src = Yc + (size_t)cv*512 + (lane & 31)*16;
                __builtin_amdgcn_global_load_lds(AS1U32(src), AS3U32(xb + (r0>>1)*PAIRB), 16, 0, 0);
            }
        }
        f32x4 acc[4][4];
        #pragma unroll
        for (int mt = 0; mt < 4; ++mt)
            #pragma unroll
            for (int nt = 0; nt < 4; ++nt) acc[mt][nt] = (f32x4){0.f,0.f,0.f,0.f};
        {
            const char* xb = Xs[p];
            #pragma unroll
            for (int c = 0; c < 8; ++c) {
                bf16x8 b[4];
                #pragma unroll
                for (int nt = 0; nt < 4; ++nt)
                    b[nt] = *(const bf16x8*)(xb + POFF(nt*16+lm) + c*64 + q*16);
                #pragma unroll
                for (int mt = 0; mt < 4; ++mt)
                    #pragma unroll
                    for (int nt = 0; nt < 4; ++nt)
                        acc[mt][nt] = __builtin_amdgcn_mfma_f32_16x16x32_bf16(wA[mt][c], b[nt], acc[mt][nt], 0,0,0);
            }
        }
        float partial[4] = {0.f,0.f,0.f,0.f};      // epilogue: relu(h1+b1).u, all fp32
        #pragma unroll
        for (int mt = 0; mt < 4; ++mt) {
            const int f0 = wave*64 + mt*16 + q*4;
            float4 bu0 = *(const float4*)&buS[f0*2];
            float4 bu1 = *(const float4*)&buS[f0*2 + 4];
            float b1v[4] = {bu0.x, bu0.z, bu1.x, bu1.z};
            float uv[4]  = {bu0.y, bu0.w, bu1.y, bu1.w};
            #pragma unroll
            for (int nt = 0; nt < 4; ++nt)
                #pragma unroll
                for (int rg = 0; rg < 4; ++rg) {
                    float h = acc[mt][nt][rg] + b1v[rg];
                    if (h > 0.f) partial[nt] += h * uv[rg];
                }
        }
        #pragma unroll
        for (int nt = 0; nt < 4; ++nt) {
            float v = partial[nt];
            v += __shfl_xor(v, 16);
            v += __shfl_xor(v, 32);
            if (lane < 16) red[wave][nt*16 + lane] = v;
        }
        if (tid < 64) {                            // meta writes for i+2 (slot p)
            colsS[p][tid] = m_ci;
            *(float4*)&posrel[p][tid][0] = m_pr;
        }
    }
    __syncthreads();
    if (tid < 64) {                                // final tile's out-store
        long e = ((long)bid + (long)(niter-1)*512)*64 + tid;
        if (e < E) out[e] = red[0][tid]+red[1][tid]+red[2][tid]+red[3][tid] + Sv;
    }
}

extern "C" void kernel_launch(void* const* d_in, const int* in_sizes, int n_in,
                              void* d_out, int out_size, void* d_ws, size_t ws_size,
                              hipStream_t stream)
{
    const float* pos_src = (const float*)d_in[0];
    const float* pos_tgt = (const float*)d_in[1];
    const float* latents = (const float*)d_in[2];
    const int*   rowi    = (const int*)d_in[3];
    const int*   coli    = (const int*)d_in[4];
    const float* Win     = (const float*)d_in[5];
    const float* b_in    = (const float*)d_in[6];
    const float* W1      = (const float*)d_in[7];
    const float* b1      = (const float*)d_in[8];
    const float* W2      = (const float*)d_in[9];
    const float* b2      = (const float*)d_in[10];
    const float* Wout    = (const float*)d_in[11];
    const float* b_out   = (const float*)d_in[12];
    float* out = (float*)d_out;
    const int E = in_sizes[3];
    const int ntiles = (E + 63) / 64;

    char* wp = (char*)d_ws;                  // packs ~264 KB + Y 51.2 MB
    char* Yc = wp + Y_OFF;

    pack_kernel<<<25, 256, 0, stream>>>(Win, W1, W2, Wout, b1, b2, b_out, wp);
    precompute_y<<<512, 256, 0, stream>>>(latents, b_in, wp, Yc);
    interp_main<<<512, 256, 0, stream>>>(pos_src, pos_tgt, rowi, coli,
                                         Win, wp, Yc, out, E, ntiles);
}